// Round 3
// baseline (803.460 us; speedup 1.0000x reference)
//
#include <hip/hip_runtime.h>
#include <hip/hip_cooperative_groups.h>
#include <math.h>

namespace cg = cooperative_groups;

#define H 1024
#define L 128
#define V 50257

// ws layout (float offsets)
#define WS_AL    0                       // 128  attn logits
#define WS_WATT  128                     // 1024 with_attention
#define WS_RNN   (128+1024)              // 1024 rnn_in
#define WS_GX    (128+2048)              // 3072
#define WS_GH    (128+2048+3072)         // 3072
#define WS_PM    (128+2048+6144)         // <=2048 partial max
#define WS_PS    (WS_PM + 2048)          // <=2048 partial sum

__device__ __forceinline__ float wred(float v) {
    v += __shfl_down(v, 32);
    v += __shfl_down(v, 16);
    v += __shfl_down(v, 8);
    v += __shfl_down(v, 4);
    v += __shfl_down(v, 2);
    v += __shfl_down(v, 1);
    return v;
}

// Single cooperative kernel: 6 phases separated by grid.sync().
// All phase work distributions are grid-stride so any grid size >= 16 blocks
// is correct; target 1792 blocks (7/CU) for co-residency headroom.
__global__ __launch_bounds__(256, 7) void k_fused(
        const int* __restrict__ x, const float* __restrict__ hid,
        const float* __restrict__ enc, const float* __restrict__ emb,
        const float* __restrict__ attn_W, const float* __restrict__ attn_b,
        const float* __restrict__ comb_W, const float* __restrict__ comb_b,
        const float* __restrict__ W_ih, const float* __restrict__ W_hh,
        const float* __restrict__ b_ih, const float* __restrict__ b_hh,
        const float* __restrict__ out_W, const float* __restrict__ out_b,
        float* __restrict__ ws, float* __restrict__ out) {
    cg::grid_group grid = cg::this_grid();
    __shared__ float sA[H];     // P2: sl[0:128]+swt[128:256]; P5: h_new
    __shared__ float sB[512];   // P2: part[256]; P5: sm/ss[8]; P6: sm[256]+ss[256]

    const int t    = threadIdx.x;
    const int lane = t & 63;
    const int wid  = t >> 6;
    const int nb   = gridDim.x;
    const int nw   = nb * 4;
    const int gw   = blockIdx.x * 4 + wid;
    const float* er = emb + (size_t)x[0] * H;

    // ---- P1: attn logits (rows 0..127) + gh = W_hh@h0 + b_hh (rows 128..3199)
    for (int w = gw; w < L + 3 * H; w += nw) {
        if (w < L) {
            const float* aw = attn_W + (size_t)w * (2 * H);
            float acc = 0.f;
            #pragma unroll
            for (int k = 0; k < 8; ++k) {
                int j = (k * 64 + lane) * 4;
                float4 wv = *(const float4*)(aw + j);
                const float* src = (j < H) ? (er + j) : (hid + (j - H));
                float4 cv = *(const float4*)src;
                acc += wv.x * cv.x + wv.y * cv.y + wv.z * cv.z + wv.w * cv.w;
            }
            acc = wred(acc);
            if (lane == 0) ws[WS_AL + w] = acc + attn_b[w];
        } else {
            int r = w - L;
            const float* wr = W_hh + (size_t)r * H;
            float acc = 0.f;
            #pragma unroll
            for (int k = 0; k < 4; ++k) {
                int j = (k * 64 + lane) * 4;
                float4 wv = *(const float4*)(wr + j);
                float4 hv = *(const float4*)(hid + j);
                acc += wv.x * hv.x + wv.y * hv.y + wv.z * hv.z + wv.w * hv.w;
            }
            acc = wred(acc);
            if (lane == 0) ws[WS_GH + r] = acc + b_hh[r];
        }
    }
    grid.sync();

    // ---- P2: softmax(128) redundant per block + with_attention (16 col-groups)
    {
        if (t < L) sA[t] = ws[WS_AL + t];
        __syncthreads();
        float m = -1e30f;
        #pragma unroll 8
        for (int i = 0; i < L; ++i) m = fmaxf(m, sA[i]);
        float s = 0.f;
        #pragma unroll 4
        for (int i = 0; i < L; ++i) s += expf(sA[i] - m);
        float inv = 1.f / s;
        if (t < L) sA[L + t] = expf(sA[t] - m) * inv;
        __syncthreads();
        if (blockIdx.x == 0 && t < L) out[V + H + t] = sA[L + t];
        int col = t & 63, q = t >> 6;
        for (int g = blockIdx.x; g < 16; g += nb) {
            int h = g * 64 + col;
            float acc = 0.f;
            #pragma unroll 8
            for (int l = q * 32; l < q * 32 + 32; ++l)
                acc += sA[L + l] * enc[l * H + h];
            sB[q * 64 + col] = acc;
            __syncthreads();
            if (q == 0)
                ws[WS_WATT + h] = sB[col] + sB[64 + col] + sB[128 + col] + sB[192 + col];
            __syncthreads();
        }
    }
    grid.sync();

    // ---- P3: rnn_in = relu(comb_W @ cat(emb_row, watt) + comb_b), wave/row
    for (int row = gw; row < H; row += nw) {
        const float* w = comb_W + (size_t)row * (2 * H);
        const float* watt = ws + WS_WATT;
        float acc = 0.f;
        #pragma unroll
        for (int k = 0; k < 8; ++k) {
            int j = (k * 64 + lane) * 4;
            float4 wv = *(const float4*)(w + j);
            const float* src = (j < H) ? (er + j) : (watt + (j - H));
            float4 cv = *(const float4*)src;
            acc += wv.x * cv.x + wv.y * cv.y + wv.z * cv.z + wv.w * cv.w;
        }
        acc = wred(acc);
        if (lane == 0) ws[WS_RNN + row] = fmaxf(acc + comb_b[row], 0.f);
    }
    grid.sync();

    // ---- P4: gx = W_ih @ rnn_in + b_ih, wave/row over 3072
    for (int r = gw; r < 3 * H; r += nw) {
        const float* w = W_ih + (size_t)r * H;
        const float* rn = ws + WS_RNN;
        float acc = 0.f;
        #pragma unroll
        for (int k = 0; k < 4; ++k) {
            int j = (k * 64 + lane) * 4;
            float4 wv = *(const float4*)(w + j);
            float4 rv = *(const float4*)(rn + j);
            acc += wv.x * rv.x + wv.y * rv.y + wv.z * rv.z + wv.w * rv.w;
        }
        acc = wred(acc);
        if (lane == 0) ws[WS_GX + r] = acc + b_ih[r];
    }
    grid.sync();

    // ---- P5: per-block GRU rebuild into LDS + vocab matvec + online-lse partials
    {
        const float* gx = ws + WS_GX;
        const float* gh = ws + WS_GH;
        #pragma unroll
        for (int i = t; i < H; i += 256) {
            float r = 1.f / (1.f + expf(-(gx[i] + gh[i])));
            float z = 1.f / (1.f + expf(-(gx[H + i] + gh[H + i])));
            float n = tanhf(gx[2 * H + i] + r * gh[2 * H + i]);
            float hn = (1.f - z) * n + z * hid[i];
            sA[i] = hn;
            if (blockIdx.x == 0) out[V + i] = hn;
        }
        __syncthreads();
        float m = -INFINITY, s = 0.f;
        for (int row = gw; row < V; row += nw) {
            const float* w = out_W + (size_t)row * H;
            float acc = 0.f;
            #pragma unroll
            for (int k = 0; k < 4; ++k) {
                int j = (k * 64 + lane) * 4;
                float4 wv = *(const float4*)(w + j);
                float4 hv = *(const float4*)(sA + j);
                acc += wv.x * hv.x + wv.y * hv.y + wv.z * hv.z + wv.w * hv.w;
            }
            acc = wred(acc);
            if (lane == 0) {
                float logit = acc + out_b[row];
                out[row] = logit;
                if (logit > m) { s = s * expf(m - logit) + 1.f; m = logit; }
                else           { s += expf(logit - m); }
            }
        }
        if (lane == 0) { sB[wid] = m; sB[4 + wid] = s; }
        __syncthreads();
        if (t == 0) {
            float M = fmaxf(fmaxf(sB[0], sB[1]), fmaxf(sB[2], sB[3]));
            float S = sB[4] * expf(sB[0] - M) + sB[5] * expf(sB[1] - M)
                    + sB[6] * expf(sB[2] - M) + sB[7] * expf(sB[3] - M);
            ws[WS_PM + blockIdx.x] = M;
            ws[WS_PS + blockIdx.x] = S;
        }
    }
    grid.sync();

    // ---- P6: redundant lse reduce over nb partials + subtract on own rows
    {
        float m = -INFINITY, s = 0.f;
        for (int i = t; i < nb; i += 256) {
            float mi = ws[WS_PM + i], si = ws[WS_PS + i];
            float M = fmaxf(m, mi);
            s = s * expf(m - M) + si * expf(mi - M);
            m = M;
        }
        sB[t] = m; sB[256 + t] = s;
        __syncthreads();
        for (int off = 128; off > 0; off >>= 1) {
            if (t < off) {
                float m2 = sB[t + off], s2 = sB[256 + t + off];
                float M = fmaxf(sB[t], m2);
                sB[256 + t] = sB[256 + t] * expf(sB[t] - M) + s2 * expf(m2 - M);
                sB[t] = M;
            }
            __syncthreads();
        }
        float lse = sB[0] + logf(sB[256]);
        for (int i = blockIdx.x * 256 + t; i < V; i += nb * 256)
            out[i] -= lse;
    }
}

extern "C" void kernel_launch(void* const* d_in, const int* in_sizes, int n_in,
                              void* d_out, int out_size, void* d_ws, size_t ws_size,
                              hipStream_t stream) {
    const int*   x      = (const int*)  d_in[0];
    const float* hidden = (const float*)d_in[1];
    const float* enc    = (const float*)d_in[2];
    const float* emb    = (const float*)d_in[3];
    const float* attn_W = (const float*)d_in[4];
    const float* attn_b = (const float*)d_in[5];
    const float* comb_W = (const float*)d_in[6];
    const float* comb_b = (const float*)d_in[7];
    const float* W_ih   = (const float*)d_in[8];
    const float* W_hh   = (const float*)d_in[9];
    const float* b_ih   = (const float*)d_in[10];
    const float* b_hh   = (const float*)d_in[11];
    const float* out_W  = (const float*)d_in[12];
    const float* out_b  = (const float*)d_in[13];
    float* out = (float*)d_out;
    float* ws  = (float*)d_ws;

    int maxb = 0;
    if (hipOccupancyMaxActiveBlocksPerMultiprocessor(&maxb, k_fused, 256, 0)
            != hipSuccess || maxb < 1)
        maxb = 4;
    int nb = maxb * 256;
    if (nb > 1792) nb = 1792;   // 7 blocks/CU target; grid-stride handles any nb

    void* args[] = {(void*)&x, (void*)&hidden, (void*)&enc, (void*)&emb,
                    (void*)&attn_W, (void*)&attn_b, (void*)&comb_W, (void*)&comb_b,
                    (void*)&W_ih, (void*)&W_hh, (void*)&b_ih, (void*)&b_hh,
                    (void*)&out_W, (void*)&out_b, (void*)&ws, (void*)&out};
    hipLaunchCooperativeKernel((void*)k_fused, dim3(nb), dim3(256), args, 0, stream);
}